// Round 14
// baseline (91.408 us; speedup 1.0000x reference)
//
#include <hip/hip_runtime.h>

typedef __attribute__((ext_vector_type(8))) _Float16 f16x8;
typedef __attribute__((ext_vector_type(4))) float f32x4;

#define BHn 64
#define Nn 1024

static constexpr int kOutMvElems = 8 * 8 * 1024 * 128;      // 8388608
static constexpr float kScaleLog2e = 0.11405506f;           // log2(e)/sqrt(160)
static constexpr unsigned kNegMask = 0xBF1Cu;               // BLADE_METRIC<0 bit i
static constexpr int kBlob = 20480;  // f16 per (bh,64-key tile) blob: K 10240 | V 10240
// K image: p=d/8 (0..19), key 0..63 -> f16 off = p*512 + key*8   (conflict-free b128 reads)
// V image: s=slot/8 (0..7), d 0..159 -> f16 off = 10240 + s*1280 + d*8
//   (slots sigma-permuted per 32-key chunk: slot 8g+i -> key 4g+i (i<4), 16+4g+(i-4) (i>=4))

typedef __attribute__((address_space(1))) const void* gas1_t;
typedef __attribute__((address_space(3))) void* las3_t;
__device__ __forceinline__ void dma16(const _Float16* g, _Float16* l) {
  __builtin_amdgcn_global_load_lds((gas1_t)g, (las3_t)l, 16, 0, 0);
}

// ---------------- fused pack: f32 (mv|s) -> K image + V image per (bh,tile) ----------------
__global__ __launch_bounds__(256) void pack_kernel(const float* __restrict__ kmv,
                                                   const float* __restrict__ ks,
                                                   const float* __restrict__ vmv,
                                                   const float* __restrict__ vs,
                                                   _Float16* __restrict__ KV) {
  __shared__ _Float16 tk[64][184];   // [key][d] K tile (pad 184)
  __shared__ _Float16 tv[160][72];   // [d][key] V tile (pad 72)
  const int kt = blockIdx.x;
  const int bh = blockIdx.y;
  const int tid = threadIdx.x;
#pragma unroll
  for (int i = 0; i < 5; ++i) {
    int s = tid + 256 * i;           // 1280 segs: key*20+p
    int key = s / 20, p = s - key * 20;
    int row = bh * Nn + kt * 64 + key;
    const float* src = (p < 16) ? (kmv + (size_t)row * 128 + p * 8)
                                : (ks + (size_t)row * 32 + (p - 16) * 8);
    float4 a = *(const float4*)src;
    float4 b = *(const float4*)(src + 4);
    f16x8 h;
    h[0] = (_Float16)a.x; h[1] = (_Float16)a.y; h[2] = (_Float16)a.z; h[3] = (_Float16)a.w;
    h[4] = (_Float16)b.x; h[5] = (_Float16)b.y; h[6] = (_Float16)b.z; h[7] = (_Float16)b.w;
    *(f16x8*)&tk[key][p * 8] = h;
  }
  for (int s = tid; s < 64 * 40; s += 256) {
    int key = s / 40, p = s - key * 40;
    int row = bh * Nn + kt * 64 + key;
    const float* src = (p < 32) ? (vmv + (size_t)row * 128 + p * 4)
                                : (vs + (size_t)row * 32 + (p - 32) * 4);
    float4 v = *(const float4*)src;
    int d = p * 4;
    tv[d + 0][key] = (_Float16)v.x;
    tv[d + 1][key] = (_Float16)v.y;
    tv[d + 2][key] = (_Float16)v.z;
    tv[d + 3][key] = (_Float16)v.w;
  }
  __syncthreads();
  _Float16* dst = KV + ((size_t)bh * 16 + kt) * kBlob;
#pragma unroll
  for (int i = 0; i < 5; ++i) {
    int u = tid + 256 * i;           // p*64+key
    int p = u >> 6, key = u & 63;
    f16x8 h = *(const f16x8*)&tk[key][p * 8];
    *(f16x8*)&dst[p * 512 + key * 8] = h;
  }
#pragma unroll
  for (int i = 0; i < 5; ++i) {
    int u = tid + 256 * i;           // s*160+d
    int s = u / 160, d = u - s * 160;
    int c32 = (s >> 2) * 32, gg = s & 3;
    f16x8 h;
#pragma unroll
    for (int i2 = 0; i2 < 8; ++i2) {
      int key = c32 + ((i2 < 4) ? (gg * 4 + i2) : (16 + gg * 4 + (i2 - 4)));
      h[i2] = tv[d][key];
    }
    *(f16x8*)&dst[10240 + u * 8] = h;
  }
}

// --- flash attention: 8 waves x 16 rows, dbuf 80KB, 2 blocks/CU -> 16 waves/CU ---
// grid: 512 blocks (XCD-swizzled -> (qb, bh)); 512 threads = 8 waves.
__global__ __launch_bounds__(512, 2) void geo_attn_kernel(const float* __restrict__ qmv,
                                                          const float* __restrict__ qs,
                                                          const _Float16* __restrict__ KV,
                                                          float* __restrict__ out) {
  __shared__ __align__(16) _Float16 kv[2 * kBlob];  // 2 x 40 KB = 80 KB (2 blocks/CU)

  // XCD swizzle: 512 blocks, XCD x gets bh 8x..8x+7 (all 8 q-blocks each)
  const int b = blockIdx.x;
  const int sw = (b & 7) * 64 + (b >> 3);
  const int qb = sw & 7;
  const int bh = sw >> 3;

  const int tid = threadIdx.x;
  const int w = tid >> 6;
  const int l = tid & 63;
  const int g = l >> 4;
  const int nn = l & 15;

  const _Float16* blob0 = KV + (size_t)bh * 16 * kBlob;

  // ---- hoisted LDS read bases (f16 units; same for all waves) ----
  int kbase[5];
#pragma unroll
  for (int c = 0; c < 5; ++c) kbase[c] = (4 * c + g) * 512 + nn * 8;                // +128*kb
  int vbase[2];
#pragma unroll
  for (int ch = 0; ch < 2; ++ch) vbase[ch] = 10240 + (4 * ch + g) * 1280 + nn * 8;  // +128*j

  // ---- Q fragments: lane holds Q[q=nn][c*32+8g+i], metric*log2e/sqrt(d) folded ----
  f16x8 qf[5];
  {
    const size_t qbase = (size_t)(bh * Nn + qb * 128 + w * 16 + nn);
#pragma unroll
    for (int c = 0; c < 5; ++c) {
      const float* src = (c < 4) ? (qmv + qbase * 128 + c * 32 + 8 * g)
                                 : (qs + qbase * 32 + 8 * g);
      float4 a = *(const float4*)src;
      float4 bb = *(const float4*)(src + 4);
      float x[8] = {a.x, a.y, a.z, a.w, bb.x, bb.y, bb.z, bb.w};
#pragma unroll
      for (int i = 0; i < 8; ++i) {
        float v = x[i] * kScaleLog2e;
        if (c < 4) {
          int idx = ((g & 1) << 3) + i;
          v = ((kNegMask >> idx) & 1u) ? -v : v;
        }
        qf[c][i] = (_Float16)v;
      }
    }
  }

  f32x4 acc[10];
#pragma unroll
  for (int j = 0; j < 10; ++j) acc[j] = (f32x4){0.f, 0.f, 0.f, 0.f};
  // Static M=12 (log2 domain); normalization cancels M; guard keeps arbitrary-input safety.
  float Ma = 12.f, La = 0.f;

  f32x4 sa[4];
  f16x8 paf[2];

  const int laneOff = l * 8 + w * 512;
  auto stage = [&](int t, int buf) {   // one 40 KB blob: 2560 segs, 5 per thread
    const _Float16* src = blob0 + (size_t)t * kBlob + laneOff;
    _Float16* dst = &kv[buf * kBlob + w * 512];
#pragma unroll
    for (int i = 0; i < 5; ++i) dma16(src + i * 4096, dst + i * 4096 + (l * 8 - l * 8));
  };
  auto do_qk = [&](int buf) {
    const _Float16* kb_ = &kv[buf * kBlob];
#pragma unroll
    for (int kb = 0; kb < 4; ++kb) sa[kb] = (f32x4){0.f, 0.f, 0.f, 0.f};
#pragma unroll
    for (int c = 0; c < 5; ++c) {
      f16x8 kf[4];
#pragma unroll
      for (int kb = 0; kb < 4; ++kb) kf[kb] = *(const f16x8*)&kb_[kbase[c] + kb * 128];
#pragma unroll
      for (int kb = 0; kb < 4; ++kb)
        sa[kb] = __builtin_amdgcn_mfma_f32_16x16x32_f16(kf[kb], qf[c], sa[kb], 0, 0, 0);
    }
  };
  auto do_pv = [&](int buf) {
    const _Float16* vb_ = &kv[buf * kBlob];
#pragma unroll
    for (int ch = 0; ch < 2; ++ch)
#pragma unroll
      for (int j = 0; j < 10; ++j) {
        f16x8 vb = *(const f16x8*)&vb_[vbase[ch] + j * 128];
        acc[j] = __builtin_amdgcn_mfma_f32_16x16x32_f16(paf[ch], vb, acc[j], 0, 0, 0);
      }
  };
  auto do_softmax = [&]() {
    float rsa = 0.f;
#pragma unroll
    for (int kb = 0; kb < 4; ++kb) {
      const int ch = kb >> 1, off = (kb & 1) * 4;
#pragma unroll
      for (int r = 0; r < 4; ++r) {
        float pa_ = exp2f(sa[kb][r] - Ma);
        rsa += pa_;
        paf[ch][off + r] = (_Float16)pa_;
      }
    }
    // guard: P near f16 overflow -> full max/rescale (never fires for N(0,1) inputs)
    if (__builtin_expect(__any((int)(rsa > 3.2e4f)), 0)) {
      float lma = sa[0][0];
#pragma unroll
      for (int kb = 0; kb < 4; ++kb)
#pragma unroll
        for (int r = 0; r < 4; ++r) lma = fmaxf(lma, sa[kb][r]);
      lma = fmaxf(lma, __shfl_xor(lma, 16));
      lma = fmaxf(lma, __shfl_xor(lma, 32));
      float nMa = fmaxf(Ma, lma);
      float fsa = exp2f(Ma - nMa);
      Ma = nMa;
      La *= fsa;
      float fa[4];
#pragma unroll
      for (int r = 0; r < 4; ++r) fa[r] = __shfl(fsa, 4 * g + r, 16);
#pragma unroll
      for (int j = 0; j < 10; ++j)
#pragma unroll
        for (int r = 0; r < 4; ++r) acc[j][r] *= fa[r];
      rsa = 0.f;
#pragma unroll
      for (int kb = 0; kb < 4; ++kb) {
        const int ch = kb >> 1, off = (kb & 1) * 4;
#pragma unroll
        for (int r = 0; r < 4; ++r) {
          float pa_ = exp2f(sa[kb][r] - Ma);
          rsa += pa_;
          paf[ch][off + r] = (_Float16)pa_;
        }
      }
    }
    La += rsa;
  };

  // ---- pipeline: stage(0); loop t: stage(t+1)->buf^1 | QK SM PV on buf | barrier ----
  stage(0, 0);
  __syncthreads();

  for (int t = 0; t < 16; ++t) {
    const int cur = t & 1;
    if (t < 15) stage(t + 1, cur ^ 1);   // DMA flies across the whole compute phase
    __builtin_amdgcn_s_setprio(1);
    do_qk(cur);
    __builtin_amdgcn_s_setprio(0);
    do_softmax();
    __builtin_amdgcn_s_setprio(1);
    do_pv(cur);
    __builtin_amdgcn_s_setprio(0);
    __syncthreads();          // drains own DMA(t+1) + buffer flip
  }

  // ---- epilogue: reduce per-lane L partials, normalize, scatter ----
  La += __shfl_xor(La, 16);
  La += __shfl_xor(La, 32);
  float ria = 1.f / La;
  float ra[4];
#pragma unroll
  for (int r = 0; r < 4; ++r) ra[r] = __shfl(ria, 4 * g + r, 16);
  const int row0 = bh * Nn + qb * 128 + w * 16;
#pragma unroll
  for (int j = 0; j < 10; ++j) {
    const int d = 16 * j + nn;
#pragma unroll
    for (int r = 0; r < 4; ++r) {
      float v0 = acc[j][r] * ra[r];
      const int r0 = row0 + 4 * g + r;
      if (d < 128)
        out[(size_t)r0 * 128 + d] = v0;
      else
        out[(size_t)kOutMvElems + (size_t)r0 * 32 + (d - 128)] = v0;
    }
  }
}

extern "C" void kernel_launch(void* const* d_in, const int* in_sizes, int n_in,
                              void* d_out, int out_size, void* d_ws, size_t ws_size,
                              hipStream_t stream) {
  const float* qmv = (const float*)d_in[0];
  const float* kmv = (const float*)d_in[1];
  const float* vmv = (const float*)d_in[2];
  const float* qs = (const float*)d_in[3];
  const float* ks = (const float*)d_in[4];
  const float* vs = (const float*)d_in[5];
  float* out = (float*)d_out;

  _Float16* KV = (_Float16*)d_ws;   // 64 bh x 16 tiles x 20480 f16 = 41.94 MB

  pack_kernel<<<dim3(16, BHn), dim3(256), 0, stream>>>(kmv, ks, vmv, vs, KV);
  geo_attn_kernel<<<dim3(512), dim3(512), 0, stream>>>(qmv, qs, KV, out);
}

// Round 15
// 82.213 us; speedup vs baseline: 1.1118x; 1.1118x over previous
//
#include <hip/hip_runtime.h>

typedef __attribute__((ext_vector_type(8))) _Float16 f16x8;
typedef __attribute__((ext_vector_type(4))) float f32x4;

#define BHn 64
#define Nn 1024

static constexpr int kOutMvElems = 8 * 8 * 1024 * 128;      // 8388608
static constexpr float kScaleLog2e = 0.11405506f;           // log2(e)/sqrt(160)
static constexpr unsigned kNegMask = 0xBF1Cu;               // BLADE_METRIC<0 bit i
static constexpr int kBlob = 20480;  // f16 per (bh,64-key tile) blob: K 10240 | V 10240
// K image: p=d/8 (0..19), key 0..63 -> f16 off = p*512 + key*8   (conflict-free b128 reads)
// V image: s=slot/8 (0..7), d 0..159 -> f16 off = 10240 + s*1280 + d*8
//   (slots sigma-permuted per 32-key chunk: slot 8g+i -> key 4g+i (i<4), 16+4g+(i-4) (i>=4))

typedef __attribute__((address_space(1))) const void* gas1_t;
typedef __attribute__((address_space(3))) void* las3_t;
__device__ __forceinline__ void dma16(const _Float16* g, _Float16* l) {
  __builtin_amdgcn_global_load_lds((gas1_t)g, (las3_t)l, 16, 0, 0);
}

// ---------------- fused pack: f32 (mv|s) -> K image + V image per (bh,tile) ----------------
__global__ __launch_bounds__(256) void pack_kernel(const float* __restrict__ kmv,
                                                   const float* __restrict__ ks,
                                                   const float* __restrict__ vmv,
                                                   const float* __restrict__ vs,
                                                   _Float16* __restrict__ KV) {
  __shared__ _Float16 tk[64][184];   // [key][d] K tile (pad 184)
  __shared__ _Float16 tv[160][72];   // [d][key] V tile (pad 72)
  const int kt = blockIdx.x;
  const int bh = blockIdx.y;
  const int tid = threadIdx.x;
#pragma unroll
  for (int i = 0; i < 5; ++i) {
    int s = tid + 256 * i;           // 1280 segs: key*20+p
    int key = s / 20, p = s - key * 20;
    int row = bh * Nn + kt * 64 + key;
    const float* src = (p < 16) ? (kmv + (size_t)row * 128 + p * 8)
                                : (ks + (size_t)row * 32 + (p - 16) * 8);
    float4 a = *(const float4*)src;
    float4 b = *(const float4*)(src + 4);
    f16x8 h;
    h[0] = (_Float16)a.x; h[1] = (_Float16)a.y; h[2] = (_Float16)a.z; h[3] = (_Float16)a.w;
    h[4] = (_Float16)b.x; h[5] = (_Float16)b.y; h[6] = (_Float16)b.z; h[7] = (_Float16)b.w;
    *(f16x8*)&tk[key][p * 8] = h;
  }
  for (int s = tid; s < 64 * 40; s += 256) {
    int key = s / 40, p = s - key * 40;
    int row = bh * Nn + kt * 64 + key;
    const float* src = (p < 32) ? (vmv + (size_t)row * 128 + p * 4)
                                : (vs + (size_t)row * 32 + (p - 32) * 4);
    float4 v = *(const float4*)src;
    int d = p * 4;
    tv[d + 0][key] = (_Float16)v.x;
    tv[d + 1][key] = (_Float16)v.y;
    tv[d + 2][key] = (_Float16)v.z;
    tv[d + 3][key] = (_Float16)v.w;
  }
  __syncthreads();
  _Float16* dst = KV + ((size_t)bh * 16 + kt) * kBlob;
#pragma unroll
  for (int i = 0; i < 5; ++i) {
    int u = tid + 256 * i;           // p*64+key
    int p = u >> 6, key = u & 63;
    f16x8 h = *(const f16x8*)&tk[key][p * 8];
    *(f16x8*)&dst[p * 512 + key * 8] = h;
  }
#pragma unroll
  for (int i = 0; i < 5; ++i) {
    int u = tid + 256 * i;           // s*160+d
    int s = u / 160, d = u - s * 160;
    int c32 = (s >> 2) * 32, gg = s & 3;
    f16x8 h;
#pragma unroll
    for (int i2 = 0; i2 < 8; ++i2) {
      int key = c32 + ((i2 < 4) ? (gg * 4 + i2) : (16 + gg * 4 + (i2 - 4)));
      h[i2] = tv[d][key];
    }
    *(f16x8*)&dst[10240 + u * 8] = h;
  }
}

// --- flash attention: ONE 16-wave block per CU (1024 thr), 16 rows/wave, dbuf 80KB ---
// grid: 256 blocks (XCD-swizzled -> (qb, bh)); guaranteed 16 waves/CU = 4 waves/SIMD.
__global__ __launch_bounds__(1024, 1) void geo_attn_kernel(const float* __restrict__ qmv,
                                                           const float* __restrict__ qs,
                                                           const _Float16* __restrict__ KV,
                                                           float* __restrict__ out) {
  __shared__ __align__(16) _Float16 kv[2 * kBlob];  // 2 x 40 KB = 80 KB

  // XCD swizzle: 256 blocks, XCD x gets bh 8x..8x+7 (all 4 q-blocks each)
  const int b = blockIdx.x;
  const int sw = (b & 7) * 32 + (b >> 3);
  const int qb = sw & 3;
  const int bh = sw >> 2;

  const int tid = threadIdx.x;
  const int w = tid >> 6;       // 0..15
  const int l = tid & 63;
  const int g = l >> 4;
  const int nn = l & 15;

  const _Float16* blob0 = KV + (size_t)bh * 16 * kBlob;

  // ---- hoisted LDS read bases (f16 units) ----
  int kbase[5];
#pragma unroll
  for (int c = 0; c < 5; ++c) kbase[c] = (4 * c + g) * 512 + nn * 8;                // +128*kb
  int vbase[2];
#pragma unroll
  for (int ch = 0; ch < 2; ++ch) vbase[ch] = 10240 + (4 * ch + g) * 1280 + nn * 8;  // +128*j

  // ---- Q fragments: lane holds Q[q=nn][c*32+8g+i], metric*log2e/sqrt(d) folded ----
  f16x8 qf[5];
  {
    const size_t qbase = (size_t)(bh * Nn + qb * 256 + w * 16 + nn);
#pragma unroll
    for (int c = 0; c < 5; ++c) {
      const float* src = (c < 4) ? (qmv + qbase * 128 + c * 32 + 8 * g)
                                 : (qs + qbase * 32 + 8 * g);
      float4 a = *(const float4*)src;
      float4 bb = *(const float4*)(src + 4);
      float x[8] = {a.x, a.y, a.z, a.w, bb.x, bb.y, bb.z, bb.w};
#pragma unroll
      for (int i = 0; i < 8; ++i) {
        float v = x[i] * kScaleLog2e;
        if (c < 4) {
          int idx = ((g & 1) << 3) + i;
          v = ((kNegMask >> idx) & 1u) ? -v : v;
        }
        qf[c][i] = (_Float16)v;
      }
    }
  }

  f32x4 acc[10];
#pragma unroll
  for (int j = 0; j < 10; ++j) acc[j] = (f32x4){0.f, 0.f, 0.f, 0.f};
  // Static M=12 (log2 domain); normalization cancels M; guard keeps arbitrary-input safety.
  float Ma = 12.f, La = 0.f;

  f32x4 sa[4];
  f16x8 paf[2];

  // ---- staging: 2560 segs per 40 KB blob; 1024 threads -> 2 each + first 8 waves 1 more ----
  auto stage = [&](int t, int buf) {
    const _Float16* src = blob0 + (size_t)t * kBlob;
    _Float16* dst = &kv[buf * kBlob];
#pragma unroll
    for (int i = 0; i < 2; ++i) {
      int base = i * 1024 * 8 + w * 512;   // wave-uniform (f16 units)
      dma16(src + base + l * 8, dst + base);
    }
    if (w < 8) {
      int base = 2 * 1024 * 8 + w * 512;
      dma16(src + base + l * 8, dst + base);
    }
  };
  auto do_qk = [&](int buf) {
    const _Float16* kb_ = &kv[buf * kBlob];
#pragma unroll
    for (int kb = 0; kb < 4; ++kb) sa[kb] = (f32x4){0.f, 0.f, 0.f, 0.f};
#pragma unroll
    for (int c = 0; c < 5; ++c) {
      f16x8 kf[4];
#pragma unroll
      for (int kb = 0; kb < 4; ++kb) kf[kb] = *(const f16x8*)&kb_[kbase[c] + kb * 128];
#pragma unroll
      for (int kb = 0; kb < 4; ++kb)
        sa[kb] = __builtin_amdgcn_mfma_f32_16x16x32_f16(kf[kb], qf[c], sa[kb], 0, 0, 0);
    }
  };
  auto do_pv = [&](int buf) {
    const _Float16* vb_ = &kv[buf * kBlob];
#pragma unroll
    for (int ch = 0; ch < 2; ++ch)
#pragma unroll
      for (int j = 0; j < 10; ++j) {
        f16x8 vb = *(const f16x8*)&vb_[vbase[ch] + j * 128];
        acc[j] = __builtin_amdgcn_mfma_f32_16x16x32_f16(paf[ch], vb, acc[j], 0, 0, 0);
      }
  };
  auto do_softmax = [&]() {
    float rsa = 0.f;
#pragma unroll
    for (int kb = 0; kb < 4; ++kb) {
      const int ch = kb >> 1, off = (kb & 1) * 4;
#pragma unroll
      for (int r = 0; r < 4; ++r) {
        float pa_ = exp2f(sa[kb][r] - Ma);
        rsa += pa_;
        paf[ch][off + r] = (_Float16)pa_;
      }
    }
    // guard: P near f16 overflow -> full max/rescale (never fires for N(0,1) inputs)
    if (__builtin_expect(__any((int)(rsa > 3.2e4f)), 0)) {
      float lma = sa[0][0];
#pragma unroll
      for (int kb = 0; kb < 4; ++kb)
#pragma unroll
        for (int r = 0; r < 4; ++r) lma = fmaxf(lma, sa[kb][r]);
      lma = fmaxf(lma, __shfl_xor(lma, 16));
      lma = fmaxf(lma, __shfl_xor(lma, 32));
      float nMa = fmaxf(Ma, lma);
      float fsa = exp2f(Ma - nMa);
      Ma = nMa;
      La *= fsa;
      float fa[4];
#pragma unroll
      for (int r = 0; r < 4; ++r) fa[r] = __shfl(fsa, 4 * g + r, 16);
#pragma unroll
      for (int j = 0; j < 10; ++j)
#pragma unroll
        for (int r = 0; r < 4; ++r) acc[j][r] *= fa[r];
      rsa = 0.f;
#pragma unroll
      for (int kb = 0; kb < 4; ++kb) {
        const int ch = kb >> 1, off = (kb & 1) * 4;
#pragma unroll
        for (int r = 0; r < 4; ++r) {
          float pa_ = exp2f(sa[kb][r] - Ma);
          rsa += pa_;
          paf[ch][off + r] = (_Float16)pa_;
        }
      }
    }
    La += rsa;
  };

  // ---- pipeline: stage(0); loop t: stage(t+1)->buf^1 | QK SM PV on buf | barrier ----
  stage(0, 0);
  __syncthreads();

  for (int t = 0; t < 16; ++t) {
    const int cur = t & 1;
    if (t < 15) stage(t + 1, cur ^ 1);   // DMA flies across the whole compute phase
    __builtin_amdgcn_s_setprio(1);
    do_qk(cur);
    __builtin_amdgcn_s_setprio(0);
    do_softmax();
    __builtin_amdgcn_s_setprio(1);
    do_pv(cur);
    __builtin_amdgcn_s_setprio(0);
    __syncthreads();          // drains own DMA(t+1) + buffer flip
  }

  // ---- epilogue: reduce per-lane L partials, normalize, scatter ----
  La += __shfl_xor(La, 16);
  La += __shfl_xor(La, 32);
  float ria = 1.f / La;
  float ra[4];
#pragma unroll
  for (int r = 0; r < 4; ++r) ra[r] = __shfl(ria, 4 * g + r, 16);
  const int row0 = bh * Nn + qb * 256 + w * 16;
#pragma unroll
  for (int j = 0; j < 10; ++j) {
    const int d = 16 * j + nn;
#pragma unroll
    for (int r = 0; r < 4; ++r) {
      float v0 = acc[j][r] * ra[r];
      const int r0 = row0 + 4 * g + r;
      if (d < 128)
        out[(size_t)r0 * 128 + d] = v0;
      else
        out[(size_t)kOutMvElems + (size_t)r0 * 32 + (d - 128)] = v0;
    }
  }
}

extern "C" void kernel_launch(void* const* d_in, const int* in_sizes, int n_in,
                              void* d_out, int out_size, void* d_ws, size_t ws_size,
                              hipStream_t stream) {
  const float* qmv = (const float*)d_in[0];
  const float* kmv = (const float*)d_in[1];
  const float* vmv = (const float*)d_in[2];
  const float* qs = (const float*)d_in[3];
  const float* ks = (const float*)d_in[4];
  const float* vs = (const float*)d_in[5];
  float* out = (float*)d_out;

  _Float16* KV = (_Float16*)d_ws;   // 64 bh x 16 tiles x 20480 f16 = 41.94 MB

  pack_kernel<<<dim3(16, BHn), dim3(256), 0, stream>>>(kmv, ks, vmv, vs, KV);
  geo_attn_kernel<<<dim3(256), dim3(1024), 0, stream>>>(qmv, qs, KV, out);
}

// Round 16
// 76.441 us; speedup vs baseline: 1.1958x; 1.0755x over previous
//
#include <hip/hip_runtime.h>

typedef __attribute__((ext_vector_type(8))) _Float16 f16x8;
typedef __attribute__((ext_vector_type(4))) float f32x4;

#define BHn 64
#define Nn 1024

static constexpr int kOutMvElems = 8 * 8 * 1024 * 128;      // 8388608
static constexpr float kScaleLog2e = 0.11405506f;           // log2(e)/sqrt(160)
static constexpr unsigned kNegMask = 0xBF1Cu;               // BLADE_METRIC<0 bit i
static constexpr int kBlob = 20480;  // f16 per (bh,64-key tile) blob: K 10240 | V 10240
static constexpr int kPair = 2 * kBlob;  // 128-key iteration = two consecutive blobs (80 KB)
// K image: p=d/8 (0..19), key 0..63 -> f16 off = p*512 + key*8   (conflict-free b128 reads)
// V image: s=slot/8 (0..7), d 0..159 -> f16 off = 10240 + s*1280 + d*8
//   (slots sigma-permuted per 32-key chunk: slot 8g+i -> key 4g+i (i<4), 16+4g+(i-4) (i>=4))

typedef __attribute__((address_space(1))) const void* gas1_t;
typedef __attribute__((address_space(3))) void* las3_t;
__device__ __forceinline__ void dma16(const _Float16* g, _Float16* l) {
  __builtin_amdgcn_global_load_lds((gas1_t)g, (las3_t)l, 16, 0, 0);
}
__device__ __forceinline__ float fast_exp2(float x) {
  float r;
  asm("v_exp_f32 %0, %1" : "=v"(r) : "v"(x));   // D = 2^S0 (ISA §3)
  return r;
}

// ---------------- fused pack: f32 (mv|s) -> K image + V image per (bh,tile) ----------------
__global__ __launch_bounds__(256) void pack_kernel(const float* __restrict__ kmv,
                                                   const float* __restrict__ ks,
                                                   const float* __restrict__ vmv,
                                                   const float* __restrict__ vs,
                                                   _Float16* __restrict__ KV) {
  __shared__ _Float16 tk[64][184];   // [key][d] K tile (pad 184)
  __shared__ _Float16 tv[160][72];   // [d][key] V tile (pad 72)
  const int kt = blockIdx.x;
  const int bh = blockIdx.y;
  const int tid = threadIdx.x;
#pragma unroll
  for (int i = 0; i < 5; ++i) {
    int s = tid + 256 * i;           // 1280 segs: key*20+p
    int key = s / 20, p = s - key * 20;
    int row = bh * Nn + kt * 64 + key;
    const float* src = (p < 16) ? (kmv + (size_t)row * 128 + p * 8)
                                : (ks + (size_t)row * 32 + (p - 16) * 8);
    float4 a = *(const float4*)src;
    float4 b = *(const float4*)(src + 4);
    f16x8 h;
    h[0] = (_Float16)a.x; h[1] = (_Float16)a.y; h[2] = (_Float16)a.z; h[3] = (_Float16)a.w;
    h[4] = (_Float16)b.x; h[5] = (_Float16)b.y; h[6] = (_Float16)b.z; h[7] = (_Float16)b.w;
    *(f16x8*)&tk[key][p * 8] = h;
  }
  for (int s = tid; s < 64 * 40; s += 256) {
    int key = s / 40, p = s - key * 40;
    int row = bh * Nn + kt * 64 + key;
    const float* src = (p < 32) ? (vmv + (size_t)row * 128 + p * 4)
                                : (vs + (size_t)row * 32 + (p - 32) * 4);
    float4 v = *(const float4*)src;
    int d = p * 4;
    tv[d + 0][key] = (_Float16)v.x;
    tv[d + 1][key] = (_Float16)v.y;
    tv[d + 2][key] = (_Float16)v.z;
    tv[d + 3][key] = (_Float16)v.w;
  }
  __syncthreads();
  _Float16* dst = KV + ((size_t)bh * 16 + kt) * kBlob;
#pragma unroll
  for (int i = 0; i < 5; ++i) {
    int u = tid + 256 * i;           // p*64+key
    int p = u >> 6, key = u & 63;
    f16x8 h = *(const f16x8*)&tk[key][p * 8];
    *(f16x8*)&dst[p * 512 + key * 8] = h;
  }
#pragma unroll
  for (int i = 0; i < 5; ++i) {
    int u = tid + 256 * i;           // s*160+d
    int s = u / 160, d = u - s * 160;
    int c32 = (s >> 2) * 32, gg = s & 3;
    f16x8 h;
#pragma unroll
    for (int i2 = 0; i2 < 8; ++i2) {
      int key = c32 + ((i2 < 4) ? (gg * 4 + i2) : (16 + gg * 4 + (i2 - 4)));
      h[i2] = tv[d][key];
    }
    *(f16x8*)&dst[10240 + u * 8] = h;
  }
}

// --- flash attention: 8 waves x 32 rows, KVBLK=128 pairs, dbuf 160KB, 8 iters ---
// launch_bounds(512,1): VGPR cap 256 -> room for windowed LDS-frag prefetch (the R16 test).
// grid: 256 blocks (XCD-swizzled -> (qb, bh)); 512 threads = 8 waves.
__global__ __launch_bounds__(512, 1) void geo_attn_kernel(const float* __restrict__ qmv,
                                                          const float* __restrict__ qs,
                                                          const _Float16* __restrict__ KV,
                                                          float* __restrict__ out) {
  __shared__ __align__(16) _Float16 kv[2 * kPair];  // 2 x 80 KB = full 160 KB pool

  // XCD swizzle: 256 blocks, XCD x gets bh 8x..8x+7 (all 4 q-blocks each)
  const int b = blockIdx.x;
  const int sw = (b & 7) * 32 + (b >> 3);
  const int qb = sw & 3;
  const int bh = sw >> 2;

  const int tid = threadIdx.x;
  const int w = tid >> 6;
  const int l = tid & 63;
  const int g = l >> 4;
  const int nn = l & 15;

  const _Float16* blob0 = KV + (size_t)bh * 16 * kBlob;

  // ---- hoisted LDS read bases (f16 units, within one 64-key blob) ----
  int kbase[5];
#pragma unroll
  for (int c = 0; c < 5; ++c) kbase[c] = (4 * c + g) * 512 + nn * 8;                // +128*kb
  int vbase[2];
#pragma unroll
  for (int ch = 0; ch < 2; ++ch) vbase[ch] = 10240 + (4 * ch + g) * 1280 + nn * 8;  // +128*j

  // ---- Q fragments: lane holds Q[q=nn(+16)][c*32+8g+i], metric*log2e/sqrt(d) folded ----
  f16x8 qf[2][5];
#pragma unroll
  for (int q2 = 0; q2 < 2; ++q2) {
    const size_t qbase = (size_t)(bh * Nn + qb * 256 + w * 32 + q2 * 16 + nn);
#pragma unroll
    for (int c = 0; c < 5; ++c) {
      const float* src = (c < 4) ? (qmv + qbase * 128 + c * 32 + 8 * g)
                                 : (qs + qbase * 32 + 8 * g);
      float4 a = *(const float4*)src;
      float4 bb = *(const float4*)(src + 4);
      float x[8] = {a.x, a.y, a.z, a.w, bb.x, bb.y, bb.z, bb.w};
#pragma unroll
      for (int i = 0; i < 8; ++i) {
        float v = x[i] * kScaleLog2e;
        if (c < 4) {
          int idx = ((g & 1) << 3) + i;
          v = ((kNegMask >> idx) & 1u) ? -v : v;
        }
        qf[q2][c][i] = (_Float16)v;
      }
    }
  }

  f32x4 acc[2][10];
#pragma unroll
  for (int q2 = 0; q2 < 2; ++q2)
#pragma unroll
    for (int j = 0; j < 10; ++j) acc[q2][j] = (f32x4){0.f, 0.f, 0.f, 0.f};
  // Static M=12 (log2 domain); normalization cancels M; guard keeps arbitrary-input safety.
  float Ma = 12.f, Mb = 12.f, La = 0.f, Lb = 0.f;

  f32x4 sa[4], sb[4];
  f16x8 paf[2], pbf[2];

  const int laneOff = l * 8 + w * 512;
  auto stage = [&](int t, int buf) {   // copy one 80 KB blob-pair image
    const _Float16* src = blob0 + (size_t)t * kPair + laneOff;
    _Float16* dst = &kv[buf * kPair + laneOff];
#pragma unroll
    for (int i = 0; i < 10; ++i) dma16(src + i * 4096, dst + i * 4096);
  };

  auto do_qk = [&](const _Float16* blob) {   // one 64-key half: 20 reads (windowed), 40 MFMA
#pragma unroll
    for (int kb = 0; kb < 4; ++kb) {
      sa[kb] = (f32x4){0.f, 0.f, 0.f, 0.f};
      sb[kb] = (f32x4){0.f, 0.f, 0.f, 0.f};
    }
    f16x8 kf[5][4];
#pragma unroll
    for (int c = 0; c < 2; ++c)            // preload window: c=0,1 (8 frags)
#pragma unroll
      for (int kb = 0; kb < 4; ++kb) kf[c][kb] = *(const f16x8*)&blob[kbase[c] + kb * 128];
#pragma unroll
    for (int c = 0; c < 5; ++c) {
      if (c + 2 < 5) {                     // keep 12-frag window in flight
#pragma unroll
        for (int kb = 0; kb < 4; ++kb)
          kf[c + 2][kb] = *(const f16x8*)&blob[kbase[c + 2] + kb * 128];
      }
#pragma unroll
      for (int kb = 0; kb < 4; ++kb) {
        sa[kb] = __builtin_amdgcn_mfma_f32_16x16x32_f16(kf[c][kb], qf[0][c], sa[kb], 0, 0, 0);
        sb[kb] = __builtin_amdgcn_mfma_f32_16x16x32_f16(kf[c][kb], qf[1][c], sb[kb], 0, 0, 0);
      }
    }
  };
  auto do_pv = [&](const _Float16* blob) {   // one 64-key half: 20 reads (4-ahead), 40 MFMA
    f16x8 vf[20];
#pragma unroll
    for (int i = 0; i < 4; ++i)
      vf[i] = *(const f16x8*)&blob[vbase[i / 10] + (i % 10) * 128];
#pragma unroll
    for (int i = 0; i < 20; ++i) {
      if (i + 4 < 20)
        vf[i + 4] = *(const f16x8*)&blob[vbase[(i + 4) / 10] + ((i + 4) % 10) * 128];
      const int ch = i / 10, j = i % 10;
      acc[0][j] = __builtin_amdgcn_mfma_f32_16x16x32_f16(paf[ch], vf[i], acc[0][j], 0, 0, 0);
      acc[1][j] = __builtin_amdgcn_mfma_f32_16x16x32_f16(pbf[ch], vf[i], acc[1][j], 0, 0, 0);
    }
  };
  auto do_softmax = [&]() {
    // fast path: P = exp2(s - M) directly, raw v_exp_f32
    float rsa = 0.f, rsb = 0.f;
#pragma unroll
    for (int kb = 0; kb < 4; ++kb) {
      const int ch = kb >> 1, off = (kb & 1) * 4;
#pragma unroll
      for (int r = 0; r < 4; ++r) {
        float pa_ = fast_exp2(sa[kb][r] - Ma);
        float pb_ = fast_exp2(sb[kb][r] - Mb);
        rsa += pa_; rsb += pb_;
        paf[ch][off + r] = (_Float16)pa_;
        pbf[ch][off + r] = (_Float16)pb_;
      }
    }
    // guard: any P near f16 overflow -> full max/rescale (never fires for N(0,1))
    if (__builtin_expect(__any((int)(rsa > 3.2e4f || rsb > 3.2e4f)), 0)) {
      float lma = sa[0][0], lmb = sb[0][0];
#pragma unroll
      for (int kb = 0; kb < 4; ++kb)
#pragma unroll
        for (int r = 0; r < 4; ++r) {
          lma = fmaxf(lma, sa[kb][r]);
          lmb = fmaxf(lmb, sb[kb][r]);
        }
      lma = fmaxf(lma, __shfl_xor(lma, 16)); lma = fmaxf(lma, __shfl_xor(lma, 32));
      lmb = fmaxf(lmb, __shfl_xor(lmb, 16)); lmb = fmaxf(lmb, __shfl_xor(lmb, 32));
      float nMa = fmaxf(Ma, lma); float fsa = fast_exp2(Ma - nMa); Ma = nMa;
      float nMb = fmaxf(Mb, lmb); float fsb = fast_exp2(Mb - nMb); Mb = nMb;
      La *= fsa; Lb *= fsb;
      float fa[4], fb[4];
#pragma unroll
      for (int r = 0; r < 4; ++r) {
        fa[r] = __shfl(fsa, 4 * g + r, 16);
        fb[r] = __shfl(fsb, 4 * g + r, 16);
      }
#pragma unroll
      for (int j = 0; j < 10; ++j)
#pragma unroll
        for (int r = 0; r < 4; ++r) {
          acc[0][j][r] *= fa[r];
          acc[1][j][r] *= fb[r];
        }
      rsa = 0.f; rsb = 0.f;
#pragma unroll
      for (int kb = 0; kb < 4; ++kb) {
        const int ch = kb >> 1, off = (kb & 1) * 4;
#pragma unroll
        for (int r = 0; r < 4; ++r) {
          float pa_ = fast_exp2(sa[kb][r] - Ma);
          float pb_ = fast_exp2(sb[kb][r] - Mb);
          rsa += pa_; rsb += pb_;
          paf[ch][off + r] = (_Float16)pa_;
          pbf[ch][off + r] = (_Float16)pb_;
        }
      }
    }
    La += rsa;
    Lb += rsb;
  };

  // ---- pipeline: 8 iters of 128 keys; stage(t+1) flies across both half-tiles ----
  stage(0, 0);
  __syncthreads();

  for (int t = 0; t < 8; ++t) {
    const int cur = t & 1;
    if (t < 7) stage(t + 1, cur ^ 1);
    const _Float16* base = &kv[cur * kPair];
#pragma unroll
    for (int h = 0; h < 2; ++h) {        // two 64-key halves per iteration
      const _Float16* blob = base + h * kBlob;
      __builtin_amdgcn_s_setprio(1);
      do_qk(blob);
      __builtin_amdgcn_s_setprio(0);
      do_softmax();
      __builtin_amdgcn_s_setprio(1);
      do_pv(blob);
      __builtin_amdgcn_s_setprio(0);
    }
    __syncthreads();          // drains own DMA(t+1) + buffer flip
  }

  // ---- epilogue: reduce per-lane L partials, normalize, scatter ----
  La += __shfl_xor(La, 16); La += __shfl_xor(La, 32);
  Lb += __shfl_xor(Lb, 16); Lb += __shfl_xor(Lb, 32);
  float ria = 1.f / La, rib = 1.f / Lb;
  float ra[4], rb_[4];
#pragma unroll
  for (int r = 0; r < 4; ++r) {
    ra[r] = __shfl(ria, 4 * g + r, 16);
    rb_[r] = __shfl(rib, 4 * g + r, 16);
  }
  const int row0 = bh * Nn + qb * 256 + w * 32;
#pragma unroll
  for (int j = 0; j < 10; ++j) {
    const int d = 16 * j + nn;
#pragma unroll
    for (int r = 0; r < 4; ++r) {
      float v0 = acc[0][j][r] * ra[r];
      float v1 = acc[1][j][r] * rb_[r];
      const int r0 = row0 + 4 * g + r;
      const int r1 = row0 + 16 + 4 * g + r;
      if (d < 128) {
        out[(size_t)r0 * 128 + d] = v0;
        out[(size_t)r1 * 128 + d] = v1;
      } else {
        out[(size_t)kOutMvElems + (size_t)r0 * 32 + (d - 128)] = v0;
        out[(size_t)kOutMvElems + (size_t)r1 * 32 + (d - 128)] = v1;
      }
    }
  }
}

extern "C" void kernel_launch(void* const* d_in, const int* in_sizes, int n_in,
                              void* d_out, int out_size, void* d_ws, size_t ws_size,
                              hipStream_t stream) {
  const float* qmv = (const float*)d_in[0];
  const float* kmv = (const float*)d_in[1];
  const float* vmv = (const float*)d_in[2];
  const float* qs = (const float*)d_in[3];
  const float* ks = (const float*)d_in[4];
  const float* vs = (const float*)d_in[5];
  float* out = (float*)d_out;

  _Float16* KV = (_Float16*)d_ws;   // 64 bh x 16 tiles x 20480 f16 = 41.94 MB

  pack_kernel<<<dim3(16, BHn), dim3(256), 0, stream>>>(kmv, ks, vmv, vs, KV);
  geo_attn_kernel<<<dim3(256), dim3(512), 0, stream>>>(qmv, qs, KV, out);
}